// Round 1
// baseline (2744.986 us; speedup 1.0000x reference)
//
#include <hip/hip_runtime.h>
#include <math.h>

#define T 2048
#define D 768
#define E 8
#define FF 3072

constexpr int TILE_T = 16;
constexpr int FCHUNK = 128;

__device__ __forceinline__ float siluf(float v) {
    return v / (1.0f + __expf(-v));
}

// ---------------------------------------------------------------------------
// Kernel 1: router — logits, softmax, top-2, softmax(top-2 probs), dg gates
// ---------------------------------------------------------------------------
__global__ void router_kernel(const float* __restrict__ x,
                              const float* __restrict__ rw,
                              const float* __restrict__ rb,
                              const float* __restrict__ dgw,
                              const float* __restrict__ dgb,
                              int* __restrict__ e_arr,    // [T][2]
                              float* __restrict__ s_arr,  // [T][2]  dg*topw
                              int* __restrict__ counts) {
    int lane = threadIdx.x & 63;
    int wv = threadIdx.x >> 6;
    int t = blockIdx.x * 4 + wv;
    if (t >= T) return;

    float lg[E], dl[E];
#pragma unroll
    for (int e = 0; e < E; ++e) { lg[e] = 0.f; dl[e] = 0.f; }

    const float* xt = x + (size_t)t * D;
#pragma unroll
    for (int i = 0; i < D / 64; ++i) {
        int d = lane + 64 * i;
        float xv = xt[d];
#pragma unroll
        for (int e = 0; e < E; ++e) {
            lg[e] = fmaf(xv, rw[d * E + e], lg[e]);
            dl[e] = fmaf(xv, dgw[e * D + d], dl[e]);
        }
    }
#pragma unroll
    for (int e = 0; e < E; ++e) {
        for (int off = 32; off; off >>= 1) {
            lg[e] += __shfl_xor(lg[e], off);
            dl[e] += __shfl_xor(dl[e], off);
        }
    }
    if (lane == 0) {
        float p[E];
        float m = -1e30f;
#pragma unroll
        for (int e = 0; e < E; ++e) { lg[e] += rb[e]; m = fmaxf(m, lg[e]); }
        float s = 0.f;
#pragma unroll
        for (int e = 0; e < E; ++e) { p[e] = __expf(lg[e] - m); s += p[e]; }
        float inv = 1.0f / s;
#pragma unroll
        for (int e = 0; e < E; ++e) p[e] *= inv;

        // top-2 (ties -> lower index, matching lax.top_k)
        int i0 = 0; float b0 = p[0];
#pragma unroll
        for (int e = 1; e < E; ++e) if (p[e] > b0) { b0 = p[e]; i0 = e; }
        int i1 = -1; float b1 = -1.0f;
#pragma unroll
        for (int e = 0; e < E; ++e) if (e != i0 && p[e] > b1) { b1 = p[e]; i1 = e; }

        // softmax over the two top probabilities (b0 >= b1)
        float eb = __expf(b1 - b0);
        float w0 = 1.0f / (1.0f + eb);
        float w1 = eb / (1.0f + eb);

        float dg0 = 1.0f / (1.0f + __expf(-(dl[i0] + dgb[i0])));
        float dg1 = 1.0f / (1.0f + __expf(-(dl[i1] + dgb[i1])));

        e_arr[t * 2 + 0] = i0;
        e_arr[t * 2 + 1] = i1;
        s_arr[t * 2 + 0] = dg0 * w0;
        s_arr[t * 2 + 1] = dg1 * w1;
        atomicAdd(&counts[i0], 1);
        atomicAdd(&counts[i1], 1);
    }
}

// ---------------------------------------------------------------------------
// Kernel 2: scan — bases, cursor init, expert_load output
// ---------------------------------------------------------------------------
__global__ void scan_kernel(const int* __restrict__ counts,
                            int* __restrict__ bases,
                            int* __restrict__ cursor,
                            float* __restrict__ load_out) {
    if (threadIdx.x == 0 && blockIdx.x == 0) {
        int b = 0;
        for (int e = 0; e < E; ++e) {
            bases[e] = b;
            cursor[e] = b;
            load_out[e] = (float)counts[e];
            b += counts[e];
        }
        bases[E] = b;
    }
}

// ---------------------------------------------------------------------------
// Kernel 3: assign — scatter (token, slot) into expert-sorted segments
// ---------------------------------------------------------------------------
__global__ void assign_kernel(const int* __restrict__ e_arr,
                              int* __restrict__ cursor,
                              int* __restrict__ a_tok,
                              int* __restrict__ a_slot) {
    int t = blockIdx.x * blockDim.x + threadIdx.x;
    if (t >= T) return;
#pragma unroll
    for (int s = 0; s < 2; ++s) {
        int e = e_arr[t * 2 + s];
        int pos = atomicAdd(&cursor[e], 1);
        a_tok[pos] = t;
        a_slot[pos] = s;
    }
}

// ---------------------------------------------------------------------------
// Kernel 4: grouped FFN — per (expert, 16-token tile): h1/g3 GEMM, silu*silu,
// ff GEMM, write scaled ff rows indexed by (token, slot)
// ---------------------------------------------------------------------------
__global__ __launch_bounds__(256, 2)
void ffn_kernel(const float* __restrict__ x,
                const float* __restrict__ w1, const float* __restrict__ w1b,
                const float* __restrict__ w2, const float* __restrict__ w2b,
                const float* __restrict__ w3, const float* __restrict__ w3b,
                const int* __restrict__ bases,
                const int* __restrict__ a_tok, const int* __restrict__ a_slot,
                const float* __restrict__ s_arr,
                float* __restrict__ ffs) {
    int e = blockIdx.y;
    int cbeg = bases[e];
    int cnt = bases[e + 1] - cbeg;
    int t0 = blockIdx.x * TILE_T;
    if (t0 >= cnt) return;
    int rem = cnt - t0;
    int nt = rem < TILE_T ? rem : TILE_T;

    __shared__ float xs[TILE_T][D];        // 48 KB
    __shared__ float acts[TILE_T][FCHUNK]; // 8 KB
    __shared__ int   toks[TILE_T];
    __shared__ int   slts[TILE_T];
    __shared__ float scl[TILE_T];

    int tid = threadIdx.x;
    if (tid < TILE_T) {
        int tok = 0, sl = 0; float sc = 0.f;
        if (tid < nt) {
            int p = cbeg + t0 + tid;
            tok = a_tok[p];
            sl = a_slot[p];
            sc = s_arr[tok * 2 + sl];
        }
        toks[tid] = tok; slts[tid] = sl; scl[tid] = sc;
    }
    __syncthreads();

    // stage x tile
    for (int t = 0; t < TILE_T; ++t) {
        const float* xp = x + (size_t)toks[t] * D;
        bool v = (t < nt);
        for (int d = tid; d < D; d += 256) xs[t][d] = v ? xp[d] : 0.0f;
    }
    __syncthreads();

    float ffacc[TILE_T][3];
    {
        float b0 = w2b[e * D + tid];
        float b1 = w2b[e * D + tid + 256];
        float b2 = w2b[e * D + tid + 512];
#pragma unroll
        for (int t = 0; t < TILE_T; ++t) { ffacc[t][0] = b0; ffacc[t][1] = b1; ffacc[t][2] = b2; }
    }

    int c = tid & 127;     // f-column within chunk
    int th = tid >> 7;     // token half (0/1)
    const float* w1p = w1 + (size_t)e * D * FF;
    const float* w3p = w3 + (size_t)e * D * FF;
    const float* w2p = w2 + (size_t)e * FF * D;

    for (int f0 = 0; f0 < FF; f0 += FCHUNK) {
        float h1[8], g3[8];
        float b1v = w1b[e * FF + f0 + c];
        float b3v = w3b[e * FF + f0 + c];
#pragma unroll
        for (int j = 0; j < 8; ++j) { h1[j] = b1v; g3[j] = b3v; }

#pragma unroll 4
        for (int d = 0; d < D; ++d) {
            float a = w1p[(size_t)d * FF + f0 + c];
            float b = w3p[(size_t)d * FF + f0 + c];
#pragma unroll
            for (int j = 0; j < 8; ++j) {
                float xv = xs[th * 8 + j][d];
                h1[j] = fmaf(xv, a, h1[j]);
                g3[j] = fmaf(xv, b, g3[j]);
            }
        }

        __syncthreads(); // previous chunk's acts fully consumed
#pragma unroll
        for (int j = 0; j < 8; ++j) acts[th * 8 + j][c] = siluf(h1[j]) * siluf(g3[j]);
        __syncthreads();

#pragma unroll 2
        for (int f = 0; f < FCHUNK; ++f) {
            float wv0 = w2p[(size_t)(f0 + f) * D + tid];
            float wv1 = w2p[(size_t)(f0 + f) * D + tid + 256];
            float wv2 = w2p[(size_t)(f0 + f) * D + tid + 512];
#pragma unroll
            for (int t = 0; t < TILE_T; ++t) {
                float av = acts[t][f];
                ffacc[t][0] = fmaf(av, wv0, ffacc[t][0]);
                ffacc[t][1] = fmaf(av, wv1, ffacc[t][1]);
                ffacc[t][2] = fmaf(av, wv2, ffacc[t][2]);
            }
        }
    }

#pragma unroll
    for (int t = 0; t < TILE_T; ++t) {
        if (t < nt) {
            float s = scl[t];
            size_t o = ((size_t)toks[t] * 2 + slts[t]) * D + tid;
            ffs[o]       = s * ffacc[t][0];
            ffs[o + 256] = s * ffacc[t][1];
            ffs[o + 512] = s * ffacc[t][2];
        }
    }
}

// ---------------------------------------------------------------------------
// Kernel 5: combine — y = x + s*ff per slot, layernorm each, sum, write out
// ---------------------------------------------------------------------------
__global__ __launch_bounds__(256)
void combine_kernel(const float* __restrict__ x,
                    const float* __restrict__ ffs,
                    const int* __restrict__ e_arr,
                    const float* __restrict__ lng,
                    const float* __restrict__ lnb,
                    float* __restrict__ out) {
    int t = blockIdx.x;
    int tid = threadIdx.x;
    __shared__ float red[4][4];

    float y0[3], y1[3];
    float s0 = 0.f, q0 = 0.f, s1 = 0.f, q1 = 0.f;
#pragma unroll
    for (int m = 0; m < 3; ++m) {
        int d = tid + 256 * m;
        float xv = x[(size_t)t * D + d];
        float a = xv + ffs[((size_t)t * 2) * D + d];
        float b = xv + ffs[((size_t)t * 2 + 1) * D + d];
        y0[m] = a; y1[m] = b;
        s0 += a; q0 += a * a;
        s1 += b; q1 += b * b;
    }
    for (int off = 32; off; off >>= 1) {
        s0 += __shfl_xor(s0, off);
        q0 += __shfl_xor(q0, off);
        s1 += __shfl_xor(s1, off);
        q1 += __shfl_xor(q1, off);
    }
    int wv = tid >> 6, lane = tid & 63;
    if (lane == 0) { red[wv][0] = s0; red[wv][1] = q0; red[wv][2] = s1; red[wv][3] = q1; }
    __syncthreads();
    s0 = red[0][0] + red[1][0] + red[2][0] + red[3][0];
    q0 = red[0][1] + red[1][1] + red[2][1] + red[3][1];
    s1 = red[0][2] + red[1][2] + red[2][2] + red[3][2];
    q1 = red[0][3] + red[1][3] + red[2][3] + red[3][3];

    const float invD = 1.0f / (float)D;
    float mu0 = s0 * invD, var0 = q0 * invD - mu0 * mu0;
    float mu1 = s1 * invD, var1 = q1 * invD - mu1 * mu1;
    float r0 = rsqrtf(var0 + 1e-5f);
    float r1 = rsqrtf(var1 + 1e-5f);

    int e0 = e_arr[t * 2], e1 = e_arr[t * 2 + 1];
#pragma unroll
    for (int m = 0; m < 3; ++m) {
        int d = tid + 256 * m;
        out[(size_t)t * D + d] =
            (y0[m] - mu0) * r0 * lng[e0 * D + d] + lnb[e0 * D + d] +
            (y1[m] - mu1) * r1 * lng[e1 * D + d] + lnb[e1 * D + d];
    }
}

// ---------------------------------------------------------------------------
extern "C" void kernel_launch(void* const* d_in, const int* in_sizes, int n_in,
                              void* d_out, int out_size, void* d_ws, size_t ws_size,
                              hipStream_t stream) {
    const float* x    = (const float*)d_in[0];
    const float* rw   = (const float*)d_in[1];
    const float* rb   = (const float*)d_in[2];
    const float* dgw  = (const float*)d_in[3];
    const float* dgb  = (const float*)d_in[4];
    const float* w1   = (const float*)d_in[5];
    const float* w1b  = (const float*)d_in[6];
    const float* w2   = (const float*)d_in[7];
    const float* w2b  = (const float*)d_in[8];
    const float* w3   = (const float*)d_in[9];
    const float* w3b  = (const float*)d_in[10];
    const float* lng  = (const float*)d_in[11];
    const float* lnb  = (const float*)d_in[12];

    float* out = (float*)d_out;
    float* load_out = out + (size_t)T * D;

    int* wsi    = (int*)d_ws;
    int* counts = wsi;            // 8
    int* bases  = wsi + 8;        // 9
    int* cursor = wsi + 20;       // 8
    int* e_arr  = wsi + 32;       // 2T
    int* a_tok  = e_arr + 2 * T;  // 2T
    int* a_slot = a_tok + 2 * T;  // 2T
    float* s_arr = (float*)(a_slot + 2 * T); // 2T
    float* ffs   = s_arr + 2 * T;            // T*2*D floats (~12.6 MB)

    hipMemsetAsync(counts, 0, 8 * sizeof(int), stream);
    router_kernel<<<T / 4, 256, 0, stream>>>(x, rw, rb, dgw, dgb, e_arr, s_arr, counts);
    scan_kernel<<<1, 64, 0, stream>>>(counts, bases, cursor, load_out);
    assign_kernel<<<(T + 255) / 256, 256, 0, stream>>>(e_arr, cursor, a_tok, a_slot);
    dim3 g((2 * T + TILE_T - 1) / TILE_T, E);
    ffn_kernel<<<g, 256, 0, stream>>>(x, w1, w1b, w2, w2b, w3, w3b,
                                      bases, a_tok, a_slot, s_arr, ffs);
    combine_kernel<<<T, 256, 0, stream>>>(x, ffs, e_arr, lng, lnb, out);
}

// Round 2
// 586.477 us; speedup vs baseline: 4.6805x; 4.6805x over previous
//
#include <hip/hip_runtime.h>
#include <math.h>

#define T 2048
#define D 768
#define E 8
#define FF 3072
#define NPOS (2 * T)        // 4096 assignments
#define NFS 4
#define FSLICE (FF / NFS)   // 768

using bf16x8 = __attribute__((ext_vector_type(8))) short;
using f32x4  = __attribute__((ext_vector_type(4))) float;
using u16x8  = __attribute__((ext_vector_type(8))) unsigned short;

__device__ __forceinline__ unsigned short f2bf(float f) {
    union { float f; unsigned u; } v; v.f = f;
    unsigned r = v.u + 0x7FFF + ((v.u >> 16) & 1);
    return (unsigned short)(r >> 16);
}
__device__ __forceinline__ float bf2f(unsigned short u) {
    union { unsigned u; float f; } v; v.u = ((unsigned)u) << 16;
    return v.f;
}
__device__ __forceinline__ float siluf(float v) {
    return v / (1.0f + __expf(-v));
}

// ---------------------------------------------------------------------------
// Pre-pass: x f32 -> bf16
// ---------------------------------------------------------------------------
__global__ __launch_bounds__(256)
void convert_x_kernel(const float* __restrict__ x, unsigned short* __restrict__ xb) {
    int i = blockIdx.x * 256 + threadIdx.x;   // one 8-elem group per thread
    const float4* p = (const float4*)x + (size_t)i * 2;
    float4 a = p[0], b = p[1];
    u16x8 o;
    o[0] = f2bf(a.x); o[1] = f2bf(a.y); o[2] = f2bf(a.z); o[3] = f2bf(a.w);
    o[4] = f2bf(b.x); o[5] = f2bf(b.y); o[6] = f2bf(b.z); o[7] = f2bf(b.w);
    *((u16x8*)xb + i) = o;
}

// ---------------------------------------------------------------------------
// Pre-pass: transpose+convert  in f32 [E][R][C] -> out bf16 [E][C][R]
// ---------------------------------------------------------------------------
__global__ __launch_bounds__(256)
void transpose_convert(const float* __restrict__ in, unsigned short* __restrict__ out,
                       int R, int C) {
    __shared__ unsigned short tb[64][72];   // pad: 144B row stride, 16B aligned
    int e = blockIdx.z;
    int r0 = blockIdx.y * 64, c0 = blockIdx.x * 64;
    int tid = threadIdx.x;
    const float* ip = in + (size_t)e * R * C;
#pragma unroll
    for (int p = 0; p < 4; ++p) {
        int r = (tid >> 4) + 16 * p;
        int c = (tid & 15) * 4;
        float4 v = *(const float4*)(ip + (size_t)(r0 + r) * C + (c0 + c));
        tb[c + 0][r] = f2bf(v.x);
        tb[c + 1][r] = f2bf(v.y);
        tb[c + 2][r] = f2bf(v.z);
        tb[c + 3][r] = f2bf(v.w);
    }
    __syncthreads();
    unsigned short* op = out + (size_t)e * R * C + (size_t)c0 * R + r0;
    int c = tid >> 2;
    int rs = (tid & 3) * 16;
#pragma unroll
    for (int i = 0; i < 2; ++i) {
        u16x8 w = *(const u16x8*)&tb[c][rs + 8 * i];
        *(u16x8*)(op + (size_t)c * R + rs + 8 * i) = w;
    }
}

// ---------------------------------------------------------------------------
// Router — logits, softmax, top-2, softmax(top-2), dg gate, counts
// ---------------------------------------------------------------------------
__global__ void router_kernel(const float* __restrict__ x,
                              const float* __restrict__ rw,
                              const float* __restrict__ rb,
                              const float* __restrict__ dgw,
                              const float* __restrict__ dgb,
                              int* __restrict__ e_arr,
                              float* __restrict__ s_arr,
                              int* __restrict__ counts) {
    int lane = threadIdx.x & 63;
    int wv = threadIdx.x >> 6;
    int t = blockIdx.x * 4 + wv;
    if (t >= T) return;

    float lg[E], dl[E];
#pragma unroll
    for (int e = 0; e < E; ++e) { lg[e] = 0.f; dl[e] = 0.f; }

    const float* xt = x + (size_t)t * D;
#pragma unroll
    for (int i = 0; i < D / 64; ++i) {
        int d = lane + 64 * i;
        float xv = xt[d];
#pragma unroll
        for (int e = 0; e < E; ++e) {
            lg[e] = fmaf(xv, rw[d * E + e], lg[e]);
            dl[e] = fmaf(xv, dgw[e * D + d], dl[e]);
        }
    }
#pragma unroll
    for (int e = 0; e < E; ++e) {
        for (int off = 32; off; off >>= 1) {
            lg[e] += __shfl_xor(lg[e], off);
            dl[e] += __shfl_xor(dl[e], off);
        }
    }
    if (lane == 0) {
        float p[E];
        float m = -1e30f;
#pragma unroll
        for (int e = 0; e < E; ++e) { lg[e] += rb[e]; m = fmaxf(m, lg[e]); }
        float s = 0.f;
#pragma unroll
        for (int e = 0; e < E; ++e) { p[e] = __expf(lg[e] - m); s += p[e]; }
        float inv = 1.0f / s;
#pragma unroll
        for (int e = 0; e < E; ++e) p[e] *= inv;

        int i0 = 0; float b0 = p[0];
#pragma unroll
        for (int e = 1; e < E; ++e) if (p[e] > b0) { b0 = p[e]; i0 = e; }
        int i1 = -1; float b1 = -1.0f;
#pragma unroll
        for (int e = 0; e < E; ++e) if (e != i0 && p[e] > b1) { b1 = p[e]; i1 = e; }

        float eb = __expf(b1 - b0);
        float w0 = 1.0f / (1.0f + eb);
        float w1 = eb / (1.0f + eb);

        float dg0 = 1.0f / (1.0f + __expf(-(dl[i0] + dgb[i0])));
        float dg1 = 1.0f / (1.0f + __expf(-(dl[i1] + dgb[i1])));

        e_arr[t * 2 + 0] = i0;
        e_arr[t * 2 + 1] = i1;
        s_arr[t * 2 + 0] = dg0 * w0;
        s_arr[t * 2 + 1] = dg1 * w1;
        atomicAdd(&counts[i0], 1);
        atomicAdd(&counts[i1], 1);
    }
}

__global__ void scan_kernel(const int* __restrict__ counts,
                            int* __restrict__ bases,
                            int* __restrict__ cursor,
                            float* __restrict__ load_out) {
    if (threadIdx.x == 0 && blockIdx.x == 0) {
        int b = 0;
        for (int e = 0; e < E; ++e) {
            bases[e] = b;
            cursor[e] = b;
            load_out[e] = (float)counts[e];
            b += counts[e];
        }
        bases[E] = b;
    }
}

__global__ void assign_kernel(const int* __restrict__ e_arr,
                              int* __restrict__ cursor,
                              int* __restrict__ a_tok,
                              int* __restrict__ pos_of) {
    int t = blockIdx.x * blockDim.x + threadIdx.x;
    if (t >= T) return;
#pragma unroll
    for (int s = 0; s < 2; ++s) {
        int e = e_arr[t * 2 + s];
        int pos = atomicAdd(&cursor[e], 1);
        a_tok[pos] = t;
        pos_of[t * 2 + s] = pos;
    }
}

// ---------------------------------------------------------------------------
// FFN — bf16 MFMA. Block = (expert e = bid&7 -> XCD e, FF-slice fs, mtile loop).
// 8 waves as 2x4 grid. GEMM1 chunk(128 f-cols) -> silu -> acts LDS -> GEMM2
// accumulates 64x768 f32 in regs; bf16 partials to ffp[fs].
// ---------------------------------------------------------------------------
__global__ __launch_bounds__(512, 2)
void ffn_mfma(const unsigned short* __restrict__ xb,
              const unsigned short* __restrict__ w1t, const float* __restrict__ w1b,
              const unsigned short* __restrict__ w3t, const float* __restrict__ w3b,
              const unsigned short* __restrict__ w2t,
              const int* __restrict__ bases, const int* __restrict__ a_tok,
              unsigned short* __restrict__ ffp) {
    int b = blockIdx.x;
    int e = b & 7;
    int r = b >> 3;
    int mti0 = r & 7;
    int fs = r >> 3;
    int cbeg = bases[e], cnt = bases[e + 1] - cbeg;
    int fBase = fs * FSLICE;

    __shared__ unsigned short xs[64][776];    // pad 8: conflict-free frag reads
    __shared__ unsigned short acts[64][136];  // pad 8
    __shared__ int toks[64];

    int tid = threadIdx.x;
    int lane = tid & 63;
    int wv = tid >> 6;
    int wr = wv >> 2, wc = wv & 3;
    int l15 = lane & 15, lk = lane >> 4;

    const unsigned short* w1p = w1t + (size_t)e * FF * D;
    const unsigned short* w3p = w3t + (size_t)e * FF * D;
    const unsigned short* w2p = w2t + (size_t)e * D * FF;

    for (int mt = mti0; mt * 64 < cnt; mt += 8) {
        int base = cbeg + mt * 64;
        int nt = cnt - mt * 64; if (nt > 64) nt = 64;

        __syncthreads();
        if (tid < 64) toks[tid] = a_tok[base + (tid < nt ? tid : 0)];
        __syncthreads();
        for (int i = tid; i < 64 * 96; i += 512) {
            int row = i / 96, seg = i % 96;
            bf16x8 v = *(const bf16x8*)(xb + (size_t)toks[row] * D + seg * 8);
            *(bf16x8*)&xs[row][seg * 8] = v;
        }
        __syncthreads();

        f32x4 facc[2][12];
#pragma unroll
        for (int a = 0; a < 2; ++a)
#pragma unroll
            for (int c = 0; c < 12; ++c) facc[a][c] = f32x4{0.f, 0.f, 0.f, 0.f};

        for (int fc = 0; fc < FSLICE; fc += 128) {
            // ---- GEMM1: 64 x 128 chunk of h1 and g3 ----
            f32x4 hacc[2][2], gacc[2][2];
#pragma unroll
            for (int a = 0; a < 2; ++a)
#pragma unroll
                for (int c = 0; c < 2; ++c) {
                    hacc[a][c] = f32x4{0.f, 0.f, 0.f, 0.f};
                    gacc[a][c] = f32x4{0.f, 0.f, 0.f, 0.f};
                }

            const unsigned short* w1q = w1p + (size_t)(fBase + fc + wc * 32 + l15) * D + lk * 8;
            const unsigned short* w3q = w3p + (size_t)(fBase + fc + wc * 32 + l15) * D + lk * 8;
#pragma unroll 4
            for (int k = 0; k < D; k += 32) {
                bf16x8 a0 = *(const bf16x8*)&xs[wr * 32 + l15][k + lk * 8];
                bf16x8 a1 = *(const bf16x8*)&xs[wr * 32 + 16 + l15][k + lk * 8];
                bf16x8 b10 = *(const bf16x8*)(w1q + k);
                bf16x8 b11 = *(const bf16x8*)(w1q + 16 * D + k);
                bf16x8 b30 = *(const bf16x8*)(w3q + k);
                bf16x8 b31 = *(const bf16x8*)(w3q + 16 * D + k);
                hacc[0][0] = __builtin_amdgcn_mfma_f32_16x16x32_bf16(a0, b10, hacc[0][0], 0, 0, 0);
                hacc[1][0] = __builtin_amdgcn_mfma_f32_16x16x32_bf16(a1, b10, hacc[1][0], 0, 0, 0);
                hacc[0][1] = __builtin_amdgcn_mfma_f32_16x16x32_bf16(a0, b11, hacc[0][1], 0, 0, 0);
                hacc[1][1] = __builtin_amdgcn_mfma_f32_16x16x32_bf16(a1, b11, hacc[1][1], 0, 0, 0);
                gacc[0][0] = __builtin_amdgcn_mfma_f32_16x16x32_bf16(a0, b30, gacc[0][0], 0, 0, 0);
                gacc[1][0] = __builtin_amdgcn_mfma_f32_16x16x32_bf16(a1, b30, gacc[1][0], 0, 0, 0);
                gacc[0][1] = __builtin_amdgcn_mfma_f32_16x16x32_bf16(a0, b31, gacc[0][1], 0, 0, 0);
                gacc[1][1] = __builtin_amdgcn_mfma_f32_16x16x32_bf16(a1, b31, gacc[1][1], 0, 0, 0);
            }

            float b1v[2], b3v[2];
            b1v[0] = w1b[e * FF + fBase + fc + wc * 32 + l15];
            b1v[1] = w1b[e * FF + fBase + fc + wc * 32 + 16 + l15];
            b3v[0] = w3b[e * FF + fBase + fc + wc * 32 + l15];
            b3v[1] = w3b[e * FF + fBase + fc + wc * 32 + 16 + l15];

            __syncthreads();   // previous GEMM2 done reading acts
#pragma unroll
            for (int rt = 0; rt < 2; ++rt)
#pragma unroll
                for (int ct = 0; ct < 2; ++ct)
#pragma unroll
                    for (int j = 0; j < 4; ++j) {
                        float h = hacc[rt][ct][j] + b1v[ct];
                        float g = gacc[rt][ct][j] + b3v[ct];
                        float av = siluf(h) * siluf(g);
                        acts[wr * 32 + rt * 16 + lk * 4 + j][wc * 32 + ct * 16 + l15] = f2bf(av);
                    }
            __syncthreads();

            // ---- GEMM2 partial accumulate over this chunk ----
#pragma unroll
            for (int kk = 0; kk < 128; kk += 32) {
                bf16x8 a0 = *(const bf16x8*)&acts[wr * 32 + l15][kk + lk * 8];
                bf16x8 a1 = *(const bf16x8*)&acts[wr * 32 + 16 + l15][kk + lk * 8];
                const unsigned short* w2q =
                    w2p + (size_t)(wc * 192 + l15) * FF + fBase + fc + kk + lk * 8;
#pragma unroll
                for (int ct = 0; ct < 12; ++ct) {
                    bf16x8 bw = *(const bf16x8*)(w2q + (size_t)ct * 16 * FF);
                    facc[0][ct] = __builtin_amdgcn_mfma_f32_16x16x32_bf16(a0, bw, facc[0][ct], 0, 0, 0);
                    facc[1][ct] = __builtin_amdgcn_mfma_f32_16x16x32_bf16(a1, bw, facc[1][ct], 0, 0, 0);
                }
            }
        }

        // ---- store bf16 partials ----
#pragma unroll
        for (int rt = 0; rt < 2; ++rt)
#pragma unroll
            for (int j = 0; j < 4; ++j) {
                int row = wr * 32 + rt * 16 + lk * 4 + j;
                if (row < nt) {
                    unsigned short* op =
                        ffp + ((size_t)fs * NPOS + base + row) * D + wc * 192 + l15;
#pragma unroll
                    for (int ct = 0; ct < 12; ++ct)
                        op[ct * 16] = f2bf(facc[rt][ct][j]);
                }
            }
    }
}

// ---------------------------------------------------------------------------
// Combine — sum partials + w2b, y = x + s*ff, dual LN, sum, write out
// ---------------------------------------------------------------------------
__global__ __launch_bounds__(256)
void combine_kernel(const float* __restrict__ x,
                    const unsigned short* __restrict__ ffp,
                    const int* __restrict__ e_arr,
                    const int* __restrict__ pos_of,
                    const float* __restrict__ s_arr,
                    const float* __restrict__ w2b,
                    const float* __restrict__ lng,
                    const float* __restrict__ lnb,
                    float* __restrict__ out) {
    int t = blockIdx.x;
    int tid = threadIdx.x;
    int p0 = pos_of[t * 2], p1 = pos_of[t * 2 + 1];
    int e0 = e_arr[t * 2], e1 = e_arr[t * 2 + 1];
    float sw0 = s_arr[t * 2], sw1 = s_arr[t * 2 + 1];
    __shared__ float red[4][4];

    float y0[3], y1[3];
    float s0 = 0.f, q0 = 0.f, s1 = 0.f, q1 = 0.f;
#pragma unroll
    for (int m = 0; m < 3; ++m) {
        int d = tid + 256 * m;
        float xv = x[(size_t)t * D + d];
        float f0 = 0.f, f1 = 0.f;
#pragma unroll
        for (int fsI = 0; fsI < NFS; ++fsI) {
            f0 += bf2f(ffp[((size_t)fsI * NPOS + p0) * D + d]);
            f1 += bf2f(ffp[((size_t)fsI * NPOS + p1) * D + d]);
        }
        f0 += w2b[e0 * D + d];
        f1 += w2b[e1 * D + d];
        float a = xv + sw0 * f0;
        float bb = xv + sw1 * f1;
        y0[m] = a; y1[m] = bb;
        s0 += a; q0 += a * a;
        s1 += bb; q1 += bb * bb;
    }
    for (int off = 32; off; off >>= 1) {
        s0 += __shfl_xor(s0, off);
        q0 += __shfl_xor(q0, off);
        s1 += __shfl_xor(s1, off);
        q1 += __shfl_xor(q1, off);
    }
    int wv = tid >> 6, lane = tid & 63;
    if (lane == 0) { red[wv][0] = s0; red[wv][1] = q0; red[wv][2] = s1; red[wv][3] = q1; }
    __syncthreads();
    s0 = red[0][0] + red[1][0] + red[2][0] + red[3][0];
    q0 = red[0][1] + red[1][1] + red[2][1] + red[3][1];
    s1 = red[0][2] + red[1][2] + red[2][2] + red[3][2];
    q1 = red[0][3] + red[1][3] + red[2][3] + red[3][3];

    const float invD = 1.0f / (float)D;
    float mu0 = s0 * invD, var0 = q0 * invD - mu0 * mu0;
    float mu1 = s1 * invD, var1 = q1 * invD - mu1 * mu1;
    float r0 = rsqrtf(var0 + 1e-5f);
    float r1 = rsqrtf(var1 + 1e-5f);

#pragma unroll
    for (int m = 0; m < 3; ++m) {
        int d = tid + 256 * m;
        out[(size_t)t * D + d] =
            (y0[m] - mu0) * r0 * lng[e0 * D + d] + lnb[e0 * D + d] +
            (y1[m] - mu1) * r1 * lng[e1 * D + d] + lnb[e1 * D + d];
    }
}

// ---------------------------------------------------------------------------
extern "C" void kernel_launch(void* const* d_in, const int* in_sizes, int n_in,
                              void* d_out, int out_size, void* d_ws, size_t ws_size,
                              hipStream_t stream) {
    const float* x   = (const float*)d_in[0];
    const float* rw  = (const float*)d_in[1];
    const float* rb  = (const float*)d_in[2];
    const float* dgw = (const float*)d_in[3];
    const float* dgb = (const float*)d_in[4];
    const float* w1  = (const float*)d_in[5];
    const float* w1b = (const float*)d_in[6];
    const float* w2  = (const float*)d_in[7];
    const float* w2b = (const float*)d_in[8];
    const float* w3  = (const float*)d_in[9];
    const float* w3b = (const float*)d_in[10];
    const float* lng = (const float*)d_in[11];
    const float* lnb = (const float*)d_in[12];

    float* out = (float*)d_out;
    float* load_out = out + (size_t)T * D;

    char* w = (char*)d_ws;
    size_t off = 0;
    auto alloc = [&](size_t bytes) -> void* {
        void* p = w + off;
        off = (off + bytes + 255) & ~(size_t)255;
        return p;
    };
    int* counts   = (int*)alloc(8 * sizeof(int));
    int* bases    = (int*)alloc(9 * sizeof(int));
    int* cursor   = (int*)alloc(8 * sizeof(int));
    int* e_arr    = (int*)alloc(NPOS * sizeof(int));
    int* a_tok    = (int*)alloc(NPOS * sizeof(int));
    int* pos_of   = (int*)alloc(NPOS * sizeof(int));
    float* s_arr  = (float*)alloc(NPOS * sizeof(float));
    unsigned short* xb  = (unsigned short*)alloc((size_t)T * D * 2);
    unsigned short* w1t = (unsigned short*)alloc((size_t)E * D * FF * 2);
    unsigned short* w3t = (unsigned short*)alloc((size_t)E * D * FF * 2);
    unsigned short* w2t = (unsigned short*)alloc((size_t)E * D * FF * 2);
    unsigned short* ffp = (unsigned short*)alloc((size_t)NFS * NPOS * D * 2);

    hipMemsetAsync(counts, 0, 8 * sizeof(int), stream);
    convert_x_kernel<<<(T * D / 8) / 256, 256, 0, stream>>>(x, xb);
    transpose_convert<<<dim3(FF / 64, D / 64, E), 256, 0, stream>>>(w1, w1t, D, FF);
    transpose_convert<<<dim3(FF / 64, D / 64, E), 256, 0, stream>>>(w3, w3t, D, FF);
    transpose_convert<<<dim3(D / 64, FF / 64, E), 256, 0, stream>>>(w2, w2t, FF, D);
    router_kernel<<<T / 4, 256, 0, stream>>>(x, rw, rb, dgw, dgb, e_arr, s_arr, counts);
    scan_kernel<<<1, 64, 0, stream>>>(counts, bases, cursor, load_out);
    assign_kernel<<<(T + 255) / 256, 256, 0, stream>>>(e_arr, cursor, a_tok, pos_of);
    ffn_mfma<<<256, 512, 0, stream>>>(xb, w1t, w1b, w3t, w3b, w2t, bases, a_tok, ffp);
    combine_kernel<<<T, 256, 0, stream>>>(x, ffp, e_arr, pos_of, s_arr, w2b, lng, lnb, out);
}

// Round 3
// 288.934 us; speedup vs baseline: 9.5004x; 2.0298x over previous
//
#include <hip/hip_runtime.h>
#include <math.h>

#define T 2048
#define D 768
#define E 8
#define FF 3072
#define NPOS (2 * T)
#define MAXTILE 40

using bf16x8 = __attribute__((ext_vector_type(8))) short;
using f32x4  = __attribute__((ext_vector_type(4))) float;
using u16x8  = __attribute__((ext_vector_type(8))) unsigned short;

__device__ __forceinline__ unsigned short f2bf(float f) {
    union { float f; unsigned u; } v; v.f = f;
    unsigned r = v.u + 0x7FFF + ((v.u >> 16) & 1);
    return (unsigned short)(r >> 16);
}
__device__ __forceinline__ float bf2f(unsigned short u) {
    union { unsigned u; float f; } v; v.u = ((unsigned)u) << 16;
    return v.f;
}
__device__ __forceinline__ float siluf(float v) {
    return v / (1.0f + __expf(-v));
}
__device__ __forceinline__ void gload16(const void* g, void* l) {
    __builtin_amdgcn_global_load_lds(
        (const __attribute__((address_space(1))) void*)g,
        (__attribute__((address_space(3))) void*)l, 16, 0, 0);
}

// ---------------------------------------------------------------------------
// Pre-pass: x f32 -> bf16
// ---------------------------------------------------------------------------
__global__ __launch_bounds__(256)
void convert_x_kernel(const float* __restrict__ x, unsigned short* __restrict__ xb) {
    int i = blockIdx.x * 256 + threadIdx.x;
    const float4* p = (const float4*)x + (size_t)i * 2;
    float4 a = p[0], b = p[1];
    u16x8 o;
    o[0] = f2bf(a.x); o[1] = f2bf(a.y); o[2] = f2bf(a.z); o[3] = f2bf(a.w);
    o[4] = f2bf(b.x); o[5] = f2bf(b.y); o[6] = f2bf(b.z); o[7] = f2bf(b.w);
    *((u16x8*)xb + i) = o;
}

// ---------------------------------------------------------------------------
// Pre-pass: transpose+convert  in f32 [E][R][C] -> out bf16 [E][C][R]
// ---------------------------------------------------------------------------
__global__ __launch_bounds__(256)
void transpose_convert(const float* __restrict__ in, unsigned short* __restrict__ out,
                       int R, int C) {
    __shared__ unsigned short tb[64][72];
    int e = blockIdx.z;
    int r0 = blockIdx.y * 64, c0 = blockIdx.x * 64;
    int tid = threadIdx.x;
    const float* ip = in + (size_t)e * R * C;
#pragma unroll
    for (int p = 0; p < 4; ++p) {
        int r = (tid >> 4) + 16 * p;
        int c = (tid & 15) * 4;
        float4 v = *(const float4*)(ip + (size_t)(r0 + r) * C + (c0 + c));
        tb[c + 0][r] = f2bf(v.x);
        tb[c + 1][r] = f2bf(v.y);
        tb[c + 2][r] = f2bf(v.z);
        tb[c + 3][r] = f2bf(v.w);
    }
    __syncthreads();
    unsigned short* op = out + (size_t)e * R * C + (size_t)c0 * R + r0;
    int c = tid >> 2;
    int rs = (tid & 3) * 16;
#pragma unroll
    for (int i = 0; i < 2; ++i) {
        u16x8 w = *(const u16x8*)&tb[c][rs + 8 * i];
        *(u16x8*)(op + (size_t)c * R + rs + 8 * i) = w;
    }
}

// ---------------------------------------------------------------------------
// Router
// ---------------------------------------------------------------------------
__global__ void router_kernel(const float* __restrict__ x,
                              const float* __restrict__ rw,
                              const float* __restrict__ rb,
                              const float* __restrict__ dgw,
                              const float* __restrict__ dgb,
                              int* __restrict__ e_arr,
                              float* __restrict__ s_arr,
                              int* __restrict__ counts) {
    int lane = threadIdx.x & 63;
    int wv = threadIdx.x >> 6;
    int t = blockIdx.x * 4 + wv;
    if (t >= T) return;

    float lg[E], dl[E];
#pragma unroll
    for (int e = 0; e < E; ++e) { lg[e] = 0.f; dl[e] = 0.f; }

    const float* xt = x + (size_t)t * D;
#pragma unroll
    for (int i = 0; i < D / 64; ++i) {
        int d = lane + 64 * i;
        float xv = xt[d];
#pragma unroll
        for (int e = 0; e < E; ++e) {
            lg[e] = fmaf(xv, rw[d * E + e], lg[e]);
            dl[e] = fmaf(xv, dgw[e * D + d], dl[e]);
        }
    }
#pragma unroll
    for (int e = 0; e < E; ++e) {
        for (int off = 32; off; off >>= 1) {
            lg[e] += __shfl_xor(lg[e], off);
            dl[e] += __shfl_xor(dl[e], off);
        }
    }
    if (lane == 0) {
        float p[E];
        float m = -1e30f;
#pragma unroll
        for (int e = 0; e < E; ++e) { lg[e] += rb[e]; m = fmaxf(m, lg[e]); }
        float s = 0.f;
#pragma unroll
        for (int e = 0; e < E; ++e) { p[e] = __expf(lg[e] - m); s += p[e]; }
        float inv = 1.0f / s;
#pragma unroll
        for (int e = 0; e < E; ++e) p[e] *= inv;

        int i0 = 0; float b0 = p[0];
#pragma unroll
        for (int e = 1; e < E; ++e) if (p[e] > b0) { b0 = p[e]; i0 = e; }
        int i1 = -1; float b1 = -1.0f;
#pragma unroll
        for (int e = 0; e < E; ++e) if (e != i0 && p[e] > b1) { b1 = p[e]; i1 = e; }

        float eb = __expf(b1 - b0);
        float w0 = 1.0f / (1.0f + eb);
        float w1 = eb / (1.0f + eb);

        float dg0 = 1.0f / (1.0f + __expf(-(dl[i0] + dgb[i0])));
        float dg1 = 1.0f / (1.0f + __expf(-(dl[i1] + dgb[i1])));

        e_arr[t * 2 + 0] = i0;
        e_arr[t * 2 + 1] = i1;
        s_arr[t * 2 + 0] = dg0 * w0;
        s_arr[t * 2 + 1] = dg1 * w1;
        atomicAdd(&counts[i0], 1);
        atomicAdd(&counts[i1], 1);
    }
}

// ---------------------------------------------------------------------------
// Scan — bases, cursor, expert_load, M-tile list (expert-pure 128-row tiles)
// ---------------------------------------------------------------------------
__global__ void scan_kernel(const int* __restrict__ counts,
                            int* __restrict__ bases,
                            int* __restrict__ cursor,
                            float* __restrict__ load_out,
                            int* __restrict__ tme, int* __restrict__ tmm,
                            int* __restrict__ tml) {
    if (threadIdx.x == 0 && blockIdx.x == 0) {
        int b = 0, nt = 0;
        for (int e = 0; e < E; ++e) {
            int c = counts[e];
            bases[e] = b;
            cursor[e] = b;
            load_out[e] = (float)c;
            for (int m = 0; m < c; m += 128) {
                tme[nt] = e;
                tmm[nt] = b + m;
                tml[nt] = (c - m < 128) ? (c - m) : 128;
                ++nt;
            }
            b += c;
        }
        bases[E] = b;
        for (; nt < MAXTILE; ++nt) tme[nt] = -1;
    }
}

__global__ void assign_kernel(const int* __restrict__ e_arr,
                              int* __restrict__ cursor,
                              int* __restrict__ a_tok,
                              int* __restrict__ pos_of) {
    int t = blockIdx.x * blockDim.x + threadIdx.x;
    if (t >= T) return;
#pragma unroll
    for (int s = 0; s < 2; ++s) {
        int e = e_arr[t * 2 + s];
        int pos = atomicAdd(&cursor[e], 1);
        a_tok[pos] = t;
        pos_of[t * 2 + s] = pos;
    }
}

// ---------------------------------------------------------------------------
// GEMM1: acts[pos][f] = silu(x@w1+b1)*silu(x@w3+b3), bf16.
// Tile 128(M) x 64(F), K=768, BK=64, gload_lds staging, XOR-swizzled LDS.
// ---------------------------------------------------------------------------
__global__ __launch_bounds__(256, 2)
void gemm1_kernel(const unsigned short* __restrict__ xb,
                  const unsigned short* __restrict__ w1t, const float* __restrict__ w1b,
                  const unsigned short* __restrict__ w3t, const float* __restrict__ w3b,
                  const int* __restrict__ a_tok,
                  const int* __restrict__ tme, const int* __restrict__ tmm,
                  const int* __restrict__ tml,
                  unsigned short* __restrict__ acts) {
    int mt = blockIdx.y;
    int e = tme[mt];
    if (e < 0) return;
    int mstart = tmm[mt], mlen = tml[mt];
    int fBase = blockIdx.x * 64;

    __shared__ char As[2][16384];
    __shared__ char Bs[2][16384];   // [0,8K)=w1 tile, [8K,16K)=w3 tile

    int tid = threadIdx.x;
    int lane = tid & 63, wv = tid >> 6;
    int wr = wv & 1, wc = wv >> 1;
    int l15 = lane & 15, lk = lane >> 4;
    int lrow = lane >> 3;                          // row within 8-row chunk
    int swl = (((lane & 7) ^ lrow) << 4);          // swizzled 16B-granule offset

    const char* xbp = (const char*)xb;
    size_t aoff[4];
#pragma unroll
    for (int i = 0; i < 4; ++i) {
        int r = (wv + 4 * i) * 8 + lrow;
        int rr = r < mlen ? r : mlen - 1;
        aoff[i] = (size_t)a_tok[mstart + rr] * (D * 2) + swl;
    }
    const char* w1p = (const char*)(w1t + (size_t)e * FF * D);
    const char* w3p = (const char*)(w3t + (size_t)e * FF * D);
    size_t boff[2];
#pragma unroll
    for (int i = 0; i < 2; ++i) {
        int f = (wv + 4 * i) * 8 + lrow;
        boff[i] = (size_t)(fBase + f) * (D * 2) + swl;
    }

    auto stage = [&](int buf, int k0) {
        int kb = k0 * 2;
        char* ab = &As[buf][0];
        char* bb = &Bs[buf][0];
#pragma unroll
        for (int i = 0; i < 4; ++i)
            gload16(xbp + aoff[i] + kb, ab + (wv + 4 * i) * 1024);
#pragma unroll
        for (int i = 0; i < 2; ++i) {
            gload16(w1p + boff[i] + kb, bb + (wv + 4 * i) * 1024);
            gload16(w3p + boff[i] + kb, bb + 8192 + (wv + 4 * i) * 1024);
        }
    };

    f32x4 hacc[4][2], gacc[4][2];
#pragma unroll
    for (int m = 0; m < 4; ++m)
#pragma unroll
        for (int n = 0; n < 2; ++n) {
            hacc[m][n] = f32x4{0.f, 0.f, 0.f, 0.f};
            gacc[m][n] = f32x4{0.f, 0.f, 0.f, 0.f};
        }

    stage(0, 0);
    __syncthreads();
    for (int ks = 0; ks < 12; ++ks) {
        int cur = ks & 1;
        if (ks < 11) stage(cur ^ 1, (ks + 1) * 64);
        const char* Ab = &As[cur][0];
        const char* Bb = &Bs[cur][0];
#pragma unroll
        for (int ksub = 0; ksub < 2; ++ksub) {
            int kb = ksub * 64 + lk * 16;
            bf16x8 af[4];
#pragma unroll
            for (int m = 0; m < 4; ++m) {
                int row = wr * 64 + m * 16 + l15;
                af[m] = *(const bf16x8*)(Ab + row * 128 + (kb ^ ((row & 7) << 4)));
            }
#pragma unroll
            for (int n = 0; n < 2; ++n) {
                int rowf = wc * 32 + n * 16 + l15;
                int off = rowf * 128 + (kb ^ ((rowf & 7) << 4));
                bf16x8 b1 = *(const bf16x8*)(Bb + off);
                bf16x8 b3 = *(const bf16x8*)(Bb + 8192 + off);
#pragma unroll
                for (int m = 0; m < 4; ++m) {
                    hacc[m][n] = __builtin_amdgcn_mfma_f32_16x16x32_bf16(af[m], b1, hacc[m][n], 0, 0, 0);
                    gacc[m][n] = __builtin_amdgcn_mfma_f32_16x16x32_bf16(af[m], b3, gacc[m][n], 0, 0, 0);
                }
            }
        }
        __syncthreads();
    }

    // epilogue: silu(h)*silu(g) -> bf16 tile in LDS -> vectorized store
    unsigned short* al = (unsigned short*)&As[0][0];
    float b1v[2], b3v[2];
#pragma unroll
    for (int n = 0; n < 2; ++n) {
        int f = fBase + wc * 32 + n * 16 + l15;
        b1v[n] = w1b[e * FF + f];
        b3v[n] = w3b[e * FF + f];
    }
#pragma unroll
    for (int m = 0; m < 4; ++m)
#pragma unroll
        for (int n = 0; n < 2; ++n)
#pragma unroll
            for (int j = 0; j < 4; ++j) {
                float h = hacc[m][n][j] + b1v[n];
                float g = gacc[m][n][j] + b3v[n];
                int row = wr * 64 + m * 16 + lk * 4 + j;
                int col = wc * 32 + n * 16 + l15;
                al[row * 64 + col] = f2bf(siluf(h) * siluf(g));
            }
    __syncthreads();
    int r = tid >> 1, cb = (tid & 1) * 32;
    if (r < mlen) {
        unsigned short* gp = acts + (size_t)(mstart + r) * FF + fBase + cb;
        const unsigned short* lp = al + r * 64 + cb;
#pragma unroll
        for (int i = 0; i < 4; ++i)
            *(u16x8*)(gp + i * 8) = *(const u16x8*)(lp + i * 8);
    }
}

// ---------------------------------------------------------------------------
// GEMM2: ffs[pos][d] = acts[pos] @ w2 (raw, f32). Tile 128x128, K=3072, BK=64.
// ---------------------------------------------------------------------------
__global__ __launch_bounds__(256, 2)
void gemm2_kernel(const unsigned short* __restrict__ acts,
                  const unsigned short* __restrict__ w2t,
                  const int* __restrict__ tme, const int* __restrict__ tmm,
                  const int* __restrict__ tml,
                  float* __restrict__ ffs) {
    int mt = blockIdx.y;
    int e = tme[mt];
    if (e < 0) return;
    int mstart = tmm[mt], mlen = tml[mt];
    int nBase = blockIdx.x * 128;

    __shared__ char As[2][16384];
    __shared__ char Bs[2][16384];

    int tid = threadIdx.x;
    int lane = tid & 63, wv = tid >> 6;
    int wr = wv & 1, wc = wv >> 1;
    int l15 = lane & 15, lk = lane >> 4;
    int lrow = lane >> 3;
    int swl = (((lane & 7) ^ lrow) << 4);

    const char* ap = (const char*)acts;
    const char* w2p = (const char*)(w2t + (size_t)e * (size_t)D * FF);
    size_t aoff[4], boff[4];
#pragma unroll
    for (int i = 0; i < 4; ++i) {
        int r = (wv + 4 * i) * 8 + lrow;
        aoff[i] = (size_t)(mstart + r) * (FF * 2) + swl;
        boff[i] = (size_t)(nBase + r) * (FF * 2) + swl;
    }

    auto stage = [&](int buf, int k0) {
        int kb = k0 * 2;
        char* ab = &As[buf][0];
        char* bb = &Bs[buf][0];
#pragma unroll
        for (int i = 0; i < 4; ++i) {
            gload16(ap + aoff[i] + kb, ab + (wv + 4 * i) * 1024);
            gload16(w2p + boff[i] + kb, bb + (wv + 4 * i) * 1024);
        }
    };

    f32x4 facc[4][4];
#pragma unroll
    for (int m = 0; m < 4; ++m)
#pragma unroll
        for (int n = 0; n < 4; ++n) facc[m][n] = f32x4{0.f, 0.f, 0.f, 0.f};

    stage(0, 0);
    __syncthreads();
    for (int ks = 0; ks < 48; ++ks) {
        int cur = ks & 1;
        if (ks < 47) stage(cur ^ 1, (ks + 1) * 64);
        const char* Ab = &As[cur][0];
        const char* Bb = &Bs[cur][0];
#pragma unroll
        for (int ksub = 0; ksub < 2; ++ksub) {
            int kb = ksub * 64 + lk * 16;
            bf16x8 af[4], bf[4];
#pragma unroll
            for (int m = 0; m < 4; ++m) {
                int row = wr * 64 + m * 16 + l15;
                af[m] = *(const bf16x8*)(Ab + row * 128 + (kb ^ ((row & 7) << 4)));
            }
#pragma unroll
            for (int n = 0; n < 4; ++n) {
                int row = wc * 64 + n * 16 + l15;
                bf[n] = *(const bf16x8*)(Bb + row * 128 + (kb ^ ((row & 7) << 4)));
            }
#pragma unroll
            for (int m = 0; m < 4; ++m)
#pragma unroll
                for (int n = 0; n < 4; ++n)
                    facc[m][n] = __builtin_amdgcn_mfma_f32_16x16x32_bf16(af[m], bf[n], facc[m][n], 0, 0, 0);
        }
        __syncthreads();
    }

#pragma unroll
    for (int m = 0; m < 4; ++m)
#pragma unroll
        for (int j = 0; j < 4; ++j) {
            int row = wr * 64 + m * 16 + lk * 4 + j;
            if (row < mlen) {
                float* gp = ffs + (size_t)(mstart + row) * D + nBase + wc * 64;
#pragma unroll
                for (int n = 0; n < 4; ++n)
                    gp[n * 16 + l15] = facc[m][n][j];
            }
        }
}

// ---------------------------------------------------------------------------
// Combine — f = ff_raw + w2b; y = x + s*f per slot; dual LN; sum; out
// ---------------------------------------------------------------------------
__global__ __launch_bounds__(256)
void combine_kernel(const float* __restrict__ x,
                    const float* __restrict__ ffs,
                    const int* __restrict__ e_arr,
                    const int* __restrict__ pos_of,
                    const float* __restrict__ s_arr,
                    const float* __restrict__ w2b,
                    const float* __restrict__ lng,
                    const float* __restrict__ lnb,
                    float* __restrict__ out) {
    int t = blockIdx.x;
    int tid = threadIdx.x;
    int p0 = pos_of[t * 2], p1 = pos_of[t * 2 + 1];
    int e0 = e_arr[t * 2], e1 = e_arr[t * 2 + 1];
    float sw0 = s_arr[t * 2], sw1 = s_arr[t * 2 + 1];
    __shared__ float red[4][4];

    float y0[3], y1[3];
    float s0 = 0.f, q0 = 0.f, s1 = 0.f, q1 = 0.f;
#pragma unroll
    for (int m = 0; m < 3; ++m) {
        int d = tid + 256 * m;
        float xv = x[(size_t)t * D + d];
        float f0 = ffs[(size_t)p0 * D + d] + w2b[e0 * D + d];
        float f1 = ffs[(size_t)p1 * D + d] + w2b[e1 * D + d];
        float a = xv + sw0 * f0;
        float bb = xv + sw1 * f1;
        y0[m] = a; y1[m] = bb;
        s0 += a; q0 += a * a;
        s1 += bb; q1 += bb * bb;
    }
    for (int off = 32; off; off >>= 1) {
        s0 += __shfl_xor(s0, off);
        q0 += __shfl_xor(q0, off);
        s1 += __shfl_xor(s1, off);
        q1 += __shfl_xor(q1, off);
    }
    int wv = tid >> 6, lane = tid & 63;
    if (lane == 0) { red[wv][0] = s0; red[wv][1] = q0; red[wv][2] = s1; red[wv][3] = q1; }
    __syncthreads();
    s0 = red[0][0] + red[1][0] + red[2][0] + red[3][0];
    q0 = red[0][1] + red[1][1] + red[2][1] + red[3][1];
    s1 = red[0][2] + red[1][2] + red[2][2] + red[3][2];
    q1 = red[0][3] + red[1][3] + red[2][3] + red[3][3];

    const float invD = 1.0f / (float)D;
    float mu0 = s0 * invD, var0 = q0 * invD - mu0 * mu0;
    float mu1 = s1 * invD, var1 = q1 * invD - mu1 * mu1;
    float r0 = rsqrtf(var0 + 1e-5f);
    float r1 = rsqrtf(var1 + 1e-5f);

#pragma unroll
    for (int m = 0; m < 3; ++m) {
        int d = tid + 256 * m;
        out[(size_t)t * D + d] =
            (y0[m] - mu0) * r0 * lng[e0 * D + d] + lnb[e0 * D + d] +
            (y1[m] - mu1) * r1 * lng[e1 * D + d] + lnb[e1 * D + d];
    }
}

// ---------------------------------------------------------------------------
extern "C" void kernel_launch(void* const* d_in, const int* in_sizes, int n_in,
                              void* d_out, int out_size, void* d_ws, size_t ws_size,
                              hipStream_t stream) {
    const float* x   = (const float*)d_in[0];
    const float* rw  = (const float*)d_in[1];
    const float* rb  = (const float*)d_in[2];
    const float* dgw = (const float*)d_in[3];
    const float* dgb = (const float*)d_in[4];
    const float* w1  = (const float*)d_in[5];
    const float* w1b = (const float*)d_in[6];
    const float* w2  = (const float*)d_in[7];
    const float* w2b = (const float*)d_in[8];
    const float* w3  = (const float*)d_in[9];
    const float* w3b = (const float*)d_in[10];
    const float* lng = (const float*)d_in[11];
    const float* lnb = (const float*)d_in[12];

    float* out = (float*)d_out;
    float* load_out = out + (size_t)T * D;

    char* w = (char*)d_ws;
    size_t off = 0;
    auto alloc = [&](size_t bytes) -> void* {
        void* p = w + off;
        off = (off + bytes + 255) & ~(size_t)255;
        return p;
    };
    int* counts   = (int*)alloc(8 * sizeof(int));
    int* bases    = (int*)alloc(9 * sizeof(int));
    int* cursor   = (int*)alloc(8 * sizeof(int));
    int* e_arr    = (int*)alloc(NPOS * sizeof(int));
    int* a_tok    = (int*)alloc(NPOS * sizeof(int));
    int* pos_of   = (int*)alloc(NPOS * sizeof(int));
    float* s_arr  = (float*)alloc(NPOS * sizeof(float));
    int* tme      = (int*)alloc(MAXTILE * sizeof(int));
    int* tmm      = (int*)alloc(MAXTILE * sizeof(int));
    int* tml      = (int*)alloc(MAXTILE * sizeof(int));
    unsigned short* xb  = (unsigned short*)alloc((size_t)T * D * 2);
    unsigned short* w1t = (unsigned short*)alloc((size_t)E * D * FF * 2);
    unsigned short* w3t = (unsigned short*)alloc((size_t)E * D * FF * 2);
    unsigned short* w2t = (unsigned short*)alloc((size_t)E * D * FF * 2);
    unsigned short* acts = (unsigned short*)alloc((size_t)(NPOS + 128) * FF * 2);
    float* ffs    = (float*)alloc((size_t)(NPOS + 128) * D * 4);

    hipMemsetAsync(counts, 0, 8 * sizeof(int), stream);
    convert_x_kernel<<<(T * D / 8) / 256, 256, 0, stream>>>(x, xb);
    transpose_convert<<<dim3(FF / 64, D / 64, E), 256, 0, stream>>>(w1, w1t, D, FF);
    transpose_convert<<<dim3(FF / 64, D / 64, E), 256, 0, stream>>>(w3, w3t, D, FF);
    transpose_convert<<<dim3(D / 64, FF / 64, E), 256, 0, stream>>>(w2, w2t, FF, D);
    router_kernel<<<T / 4, 256, 0, stream>>>(x, rw, rb, dgw, dgb, e_arr, s_arr, counts);
    scan_kernel<<<1, 64, 0, stream>>>(counts, bases, cursor, load_out, tme, tmm, tml);
    assign_kernel<<<(T + 255) / 256, 256, 0, stream>>>(e_arr, cursor, a_tok, pos_of);
    gemm1_kernel<<<dim3(FF / 64, MAXTILE), 256, 0, stream>>>(
        xb, w1t, w1b, w3t, w3b, a_tok, tme, tmm, tml, acts);
    gemm2_kernel<<<dim3(D / 128, MAXTILE), 256, 0, stream>>>(
        acts, w2t, tme, tmm, tml, ffs);
    combine_kernel<<<T, 256, 0, stream>>>(x, ffs, e_arr, pos_of, s_arr, w2b, lng, lnb, out);
}